// Round 1
// baseline (1126.455 us; speedup 1.0000x reference)
//
#include <hip/hip_runtime.h>
#include <hip/hip_bf16.h>
#include <math.h>

// Problem constants
#define BATCH   16384
#define NTAB    200000
#define KNB     16
#define EDIM    256
#define HEADS   2
#define ADIM    64
#define HD      128

// ---------------- workspace layout (floats) ----------------
// T      : NTAB*128          = 25,600,000
// cpart  : BATCH*128         =  2,097,152
// glin   : BATCH*256         =  4,194,304
// comb   : BATCH*256         =  4,194,304
// W1t_rp : 256*128           =     32,768
// W1b_rp : 256*128           =     32,768
// gateRp : 256*256           =     65,536
// outRp  : 256*256           =     65,536
// total ≈ 145.2 MB
static const size_t OFF_T     = 0;
static const size_t OFF_CPART = OFF_T     + (size_t)NTAB * 128;
static const size_t OFF_GLIN  = OFF_CPART + (size_t)BATCH * 128;
static const size_t OFF_COMB  = OFF_GLIN  + (size_t)BATCH * 256;
static const size_t OFF_W1T   = OFF_COMB  + (size_t)BATCH * 256;
static const size_t OFF_W1B   = OFF_W1T   + 256 * 128;
static const size_t OFF_GATE  = OFF_W1B   + 256 * 128;
static const size_t OFF_OUTW  = OFF_GATE  + 256 * 256;

// ---------------- weight repack ----------------
// W1t_rp[f*128+c] = W1[h][f][a],  W1b_rp[f*128+c] = W1[h][256+f][a],  c = h*64+a
// gateRp[f*256+e] = block-diag padded gate_W (torch y = x @ W.T)
// outRp[f*256+e]  = out_W[e][f]
__global__ __launch_bounds__(256) void repack_kernel(
    const float* __restrict__ W1, const float* __restrict__ gateW,
    const float* __restrict__ outW,
    float* __restrict__ W1t, float* __restrict__ W1b,
    float* __restrict__ gateRp, float* __restrict__ outRp)
{
    int i = blockIdx.x * 256 + threadIdx.x;   // 0 .. 65535
    if (i < 32768) {
        int f = i >> 7, c = i & 127;
        int h = c >> 6, a = c & 63;
        W1t[i] = W1[h * 32768 + f * 64 + a];
        W1b[i] = W1[h * 32768 + (256 + f) * 64 + a];
    }
    if (i < 65536) {
        int f = i >> 8, e = i & 255;
        float v = 0.f;
        if ((f >> 7) == (e >> 7)) {
            int h = e >> 7;
            v = gateW[h * 16384 + (e & 127) * 128 + (f & 127)];
        }
        gateRp[i] = v;
        outRp[i] = outW[e * 256 + f];
    }
}

// ---------------- generic fp32 GEMM, Kdim == 256 ----------------
// C[M x Nw] = A[M x 256] @ W[256 x Nw] (+bias).  128x128 tile per block,
// 8x8 register tile per thread (256 threads).  Optional row gather of A
// (negative index -> zero row).  Optional final mask (negative -> store 0).
__global__ __launch_bounds__(256) void gemm256_kernel(
    const float* __restrict__ A, const int* __restrict__ gather,
    const float* __restrict__ W, int Nw, const float* __restrict__ bias,
    float* __restrict__ C, int M, const int* __restrict__ finalMask)
{
    __shared__ float sA[32 * 132];   // [kk][i], stride 132 (pad for banks/align)
    __shared__ float sW[32 * 128];   // [kk][c]

    const int t  = threadIdx.x;
    const int tx = t & 15;           // col group
    const int ty = t >> 4;           // row group
    const int row0    = blockIdx.x * 128;
    const int colBase = blockIdx.y * 128;

    float acc[8][8];
#pragma unroll
    for (int r = 0; r < 8; ++r)
#pragma unroll
        for (int c = 0; c < 8; ++c) acc[r][c] = 0.f;

    for (int k0 = 0; k0 < 256; k0 += 32) {
        __syncthreads();
        // stage A (transposed into LDS): flat = t + l*256; i=flat>>5 row, kk=flat&31
#pragma unroll
        for (int l = 0; l < 16; ++l) {
            int flat = t + l * 256;
            int i  = flat >> 5;
            int kk = flat & 31;
            int r  = row0 + i;
            float v = 0.f;
            if (r < M) {
                if (gather) {
                    int g = gather[r];
                    if (g >= 0) v = A[(size_t)g * 256 + k0 + kk];
                } else {
                    v = A[(size_t)r * 256 + k0 + kk];
                }
            }
            sA[kk * 132 + i] = v;
        }
        // stage W: flat = t + l*256; kk=flat>>7, c=flat&127
#pragma unroll
        for (int l = 0; l < 16; ++l) {
            int flat = t + l * 256;
            int c  = flat & 127;
            int kk = flat >> 7;
            sW[kk * 128 + c] = W[(size_t)(k0 + kk) * Nw + colBase + c];
        }
        __syncthreads();

#pragma unroll 8
        for (int kk = 0; kk < 32; ++kk) {
            const float4 a0 = *(const float4*)&sA[kk * 132 + ty * 8];
            const float4 a1 = *(const float4*)&sA[kk * 132 + ty * 8 + 4];
            const float4 w0 = *(const float4*)&sW[kk * 128 + tx * 8];
            const float4 w1 = *(const float4*)&sW[kk * 128 + tx * 8 + 4];
            const float av[8] = {a0.x, a0.y, a0.z, a0.w, a1.x, a1.y, a1.z, a1.w};
            const float wv[8] = {w0.x, w0.y, w0.z, w0.w, w1.x, w1.y, w1.z, w1.w};
#pragma unroll
            for (int r = 0; r < 8; ++r)
#pragma unroll
                for (int c = 0; c < 8; ++c)
                    acc[r][c] = fmaf(av[r], wv[c], acc[r][c]);
        }
    }

    float bv[8];
#pragma unroll
    for (int c = 0; c < 8; ++c)
        bv[c] = bias ? bias[colBase + tx * 8 + c] : 0.f;

#pragma unroll
    for (int r = 0; r < 8; ++r) {
        int row = row0 + ty * 8 + r;
        if (row < M) {
            bool zero = (finalMask != nullptr) && (finalMask[row] < 0);
            float4 o0, o1;
            o0.x = zero ? 0.f : acc[r][0] + bv[0];
            o0.y = zero ? 0.f : acc[r][1] + bv[1];
            o0.z = zero ? 0.f : acc[r][2] + bv[2];
            o0.w = zero ? 0.f : acc[r][3] + bv[3];
            o1.x = zero ? 0.f : acc[r][4] + bv[4];
            o1.y = zero ? 0.f : acc[r][5] + bv[5];
            o1.z = zero ? 0.f : acc[r][6] + bv[6];
            o1.w = zero ? 0.f : acc[r][7] + bv[7];
            float* dst = &C[(size_t)row * Nw + colBase + tx * 8];
            *(float4*)dst       = o0;
            *(float4*)(dst + 4) = o1;
        }
    }
}

// ---------------- fused epilogue: logits / softmax / agg / combine ----------------
__global__ __launch_bounds__(256) void epilogue_kernel(
    const float* __restrict__ table, const int* __restrict__ center_idx,
    const int* __restrict__ nb_idx_tab, const float* __restrict__ nb_wt_tab,
    const float* __restrict__ T, const float* __restrict__ cpart,
    const float* __restrict__ glin, const float* __restrict__ W2,
    const float* __restrict__ b2, float* __restrict__ comb)
{
    const int b = blockIdx.x;
    const int t = threadIdx.x;

    __shared__ float s_ctr[256];
    __shared__ float s_logit[32];   // [h][k]
    __shared__ float s_w[32];       // softmax weights [h][k]
    __shared__ int   s_nb[16];
    __shared__ float s_wt[16];

    const int ci   = center_idx[b];
    const int safe = ci < 0 ? 0 : ci;

    if (t < 16) {
        s_nb[t] = nb_idx_tab[(size_t)safe * KNB + t];
        s_wt[t] = nb_wt_tab[(size_t)safe * KNB + t];
    }
    if (t < 32) s_logit[t] = 0.f;
    s_ctr[t] = (ci < 0) ? 0.f : table[(size_t)ci * 256 + t];
    __syncthreads();

    // gather T rows, add center part, exact GELU, accumulate logits
#pragma unroll
    for (int l = 0; l < 8; ++l) {
        int flat = t + l * 256;          // 0..2047
        int k = flat >> 7;               // neighbor
        int c = flat & 127;              // (h,a) column
        int nb = s_nb[k];
        int ns = nb < 0 ? 0 : nb;
        float v = T[(size_t)ns * 128 + c] + cpart[(size_t)b * 128 + c];
        float g = 0.5f * v * (1.f + erff(v * 0.70710678118654752440f));
        atomicAdd(&s_logit[(c >> 6) * 16 + k], g * W2[c]);
    }
    __syncthreads();

    // softmax per head (serial, tiny)
    if (t < 2) {
        int h = t;
        bool hasany = false;
        for (int k = 0; k < 16; ++k) hasany |= (s_nb[k] >= 0);
        if (!hasany) {
            for (int k = 0; k < 16; ++k) s_w[h * 16 + k] = 1.f / 16.f;
        } else {
            float lg[16];
            float m = -INFINITY;
            for (int k = 0; k < 16; ++k) {
                float L;
                if (s_nb[k] >= 0)
                    L = s_logit[h * 16 + k] + b2[h] + logf(s_wt[k] + 1e-8f);
                else
                    L = -INFINITY;
                lg[k] = L;
                if (L > m) m = L;
            }
            float s = 0.f;
            float ex[16];
            for (int k = 0; k < 16; ++k) { ex[k] = expf(lg[k] - m); s += ex[k]; }
            float inv = 1.f / s;
            for (int k = 0; k < 16; ++k) s_w[h * 16 + k] = ex[k] * inv;
        }
    }
    __syncthreads();

    // agg over gathered neighbor rows + gated combine (t == output element e)
    const int h = t >> 7;
    float agg = 0.f;
#pragma unroll
    for (int k = 0; k < 16; ++k) {
        int nb = s_nb[k];
        int ns = nb < 0 ? 0 : nb;
        agg = fmaf(s_w[h * 16 + k], table[(size_t)ns * 256 + t], agg);
    }
    float gl   = glin[(size_t)b * 256 + t];
    float gate = 1.f / (1.f + expf(-gl));
    comb[(size_t)b * 256 + t] = s_ctr[t] + gate * agg;
}

extern "C" void kernel_launch(void* const* d_in, const int* in_sizes, int n_in,
                              void* d_out, int out_size, void* d_ws, size_t ws_size,
                              hipStream_t stream)
{
    const int*   center_idx = (const int*)  d_in[0];
    const float* emb_table  = (const float*)d_in[1];
    const int*   nb_idx     = (const int*)  d_in[2];
    const float* nb_wt      = (const float*)d_in[3];
    const float* attn_W1    = (const float*)d_in[4];
    const float* attn_b1    = (const float*)d_in[5];   // flat [128] = [h*64+a]
    const float* attn_W2    = (const float*)d_in[6];   // flat [128]
    const float* attn_b2    = (const float*)d_in[7];   // [2]
    const float* gate_W     = (const float*)d_in[8];
    const float* gate_b     = (const float*)d_in[9];   // flat [256]
    const float* out_W      = (const float*)d_in[10];
    const float* out_b      = (const float*)d_in[11];  // [256]
    float* out = (float*)d_out;

    float* ws     = (float*)d_ws;
    float* T      = ws + OFF_T;
    float* cpart  = ws + OFF_CPART;
    float* glin   = ws + OFF_GLIN;
    float* comb   = ws + OFF_COMB;
    float* W1t_rp = ws + OFF_W1T;
    float* W1b_rp = ws + OFF_W1B;
    float* gateRp = ws + OFF_GATE;
    float* outRp  = ws + OFF_OUTW;

    // 1) repack weights
    repack_kernel<<<256, 256, 0, stream>>>(attn_W1, gate_W, out_W,
                                           W1t_rp, W1b_rp, gateRp, outRp);

    // 2) T = emb_table @ W1_bot          [200000 x 256 x 128]
    gemm256_kernel<<<dim3((NTAB + 127) / 128, 1), 256, 0, stream>>>(
        emb_table, nullptr, W1b_rp, 128, nullptr, T, NTAB, nullptr);

    // 3) cpart = gather(center) @ W1_top + b1    [16384 x 256 x 128]
    gemm256_kernel<<<dim3(BATCH / 128, 1), 256, 0, stream>>>(
        emb_table, center_idx, W1t_rp, 128, attn_b1, cpart, BATCH, nullptr);

    // 4) glin = gather(center) @ gate_blockdiag + gate_b   [16384 x 256 x 256]
    gemm256_kernel<<<dim3(BATCH / 128, 2), 256, 0, stream>>>(
        emb_table, center_idx, gateRp, 256, gate_b, glin, BATCH, nullptr);

    // 5) fused epilogue -> combined
    epilogue_kernel<<<BATCH, 256, 0, stream>>>(
        emb_table, center_idx, nb_idx, nb_wt, T, cpart, glin,
        attn_W2, attn_b2, comb);

    // 6) out = combined @ out_W^T + out_b, invalid rows -> 0
    gemm256_kernel<<<dim3(BATCH / 128, 2), 256, 0, stream>>>(
        comb, nullptr, outRp, 256, out_b, out, BATCH, center_idx);
}

// Round 2
// 442.943 us; speedup vs baseline: 2.5431x; 2.5431x over previous
//
#include <hip/hip_runtime.h>
#include <hip/hip_bf16.h>
#include <math.h>

// Problem constants
#define BATCH   16384
#define NTAB    200000
#define KNB     16
#define EDIM    256
#define HEADS   2
#define ADIM    64
#define HD      128

typedef __attribute__((ext_vector_type(8))) short  short8;
typedef __attribute__((ext_vector_type(4))) float  f32x4;
typedef __attribute__((ext_vector_type(8))) unsigned short ushort8;
typedef __attribute__((ext_vector_type(4))) unsigned short ushort4v;

__device__ __forceinline__ unsigned short f2b(float f) {
    union { float f; unsigned u; } x; x.f = f;
    unsigned r = x.u + 0x7fffu + ((x.u >> 16) & 1u);
    return (unsigned short)(r >> 16);
}
__device__ __forceinline__ float b2f(unsigned short h) {
    union { unsigned u; float f; } x; x.u = ((unsigned)h) << 16;
    return x.f;
}

// ---------------- workspace layout (bytes) ----------------
// T      : 200000*128*2 = 51,200,000   (bf16)
// cg     : 16384*384*2  = 12,582,912   (bf16: [b][0:128)=cpart, [128:384)=glin)
// comb   : 16384*256*2  =  8,388,608   (bf16)
// WcatT  : 384*256*2    =    196,608   (bf16 [n][k])
// W1bT   : 128*256*2    =     65,536
// outWT  : 256*256*2    =    131,072
// bcat   : 384*4        =      1,536
static const size_t OFF_T    = 0;
static const size_t OFF_CG   = OFF_T    + (size_t)NTAB * 128 * 2;
static const size_t OFF_COMB = OFF_CG   + (size_t)BATCH * 384 * 2;
static const size_t OFF_WCAT = OFF_COMB + (size_t)BATCH * 256 * 2;
static const size_t OFF_W1B  = OFF_WCAT + 384 * 256 * 2;
static const size_t OFF_OUTW = OFF_W1B  + 128 * 256 * 2;
static const size_t OFF_BCAT = OFF_OUTW + 256 * 256 * 2;

// ---------------- weight repack (all to bf16, [n][k] layout) ----------------
__global__ __launch_bounds__(256) void repack_kernel(
    const float* __restrict__ W1, const float* __restrict__ gateW,
    const float* __restrict__ outW,
    const float* __restrict__ b1, const float* __restrict__ gateB,
    unsigned short* __restrict__ WcatT, unsigned short* __restrict__ W1bT,
    unsigned short* __restrict__ outWT, float* __restrict__ bcat)
{
    int i = blockIdx.x * 256 + threadIdx.x;   // 0 .. 98303
    // WcatT [384][256]
    {
        int c = i >> 8, f = i & 255;
        float v;
        if (c < 128) {
            int h = c >> 6, a = c & 63;
            v = W1[h * 32768 + f * 64 + a];            // top half of W1 (f<256)
        } else {
            int e = c - 128;
            int h = e >> 7;
            v = ((e >> 7) == (f >> 7)) ? gateW[h * 16384 + (e & 127) * 128 + (f & 127)] : 0.f;
        }
        WcatT[i] = f2b(v);
    }
    // W1bT [128][256]
    if (i < 32768) {
        int c = i >> 8, f = i & 255;
        int h = c >> 6, a = c & 63;
        W1bT[i] = f2b(W1[h * 32768 + (256 + f) * 64 + a]);
    }
    // outWT [256][256] : out = comb @ outW^T -> Bt[e][f] = outW[e][f] (already)
    if (i < 65536) outWT[i] = f2b(outW[i]);
    // bcat
    if (i < 384) bcat[i] = (i < 128) ? b1[i] : gateB[i - 128];
}

// ---------------- bf16 MFMA GEMM, K == 256, 128x128 tile ----------------
// AMODE: 0 = A fp32 direct rows, 1 = A fp32 gathered rows, 2 = A bf16 direct
// C[M x Nw] = A[M x 256] @ Wt^T  (Wt stored [n][k] bf16)
template<int AMODE, bool OUT_BF16, bool HAS_BIAS, bool HAS_MASK>
__global__ __launch_bounds__(256) void gemm_mfma(
    const float* __restrict__ Af, const unsigned short* __restrict__ Ab,
    const int* __restrict__ gather,
    const unsigned short* __restrict__ Wt, int Nw,
    const float* __restrict__ bias, const int* __restrict__ mask,
    void* __restrict__ Cout, int M)
{
    __shared__ unsigned short sA[128 * 40];   // [row][k] pad 32->40 (conflict-free)
    __shared__ unsigned short sB[128 * 32];   // [n][k]   (global_load_lds layout)
    __shared__ int s_idx[128];

    const int t = threadIdx.x;
    const int row0    = blockIdx.x * 128;
    const int colBase = blockIdx.y * 128;

    if (AMODE == 1 && t < 128) s_idx[t] = gather[row0 + t];

    const int wv   = t >> 6;
    const int wr   = wv >> 1, wc = wv & 1;
    const int lane = t & 63;
    const int l15  = lane & 15;
    const int quad = lane >> 4;

    f32x4 acc[4][4];
#pragma unroll
    for (int a = 0; a < 4; ++a)
#pragma unroll
        for (int b = 0; b < 4; ++b) acc[a][b] = (f32x4)0.f;

    for (int k0 = 0; k0 < 256; k0 += 32) {
        __syncthreads();
        // ---- stage A ----
        if (AMODE == 2) {
#pragma unroll
            for (int l = 0; l < 2; ++l) {
                int p = t + l * 256;            // 0..511
                int row = p >> 2, seg = p & 3;  // 8 bf16 per chunk
                int sr = row0 + row; if (sr > M - 1) sr = M - 1;
                ushort8 v = *(const ushort8*)&Ab[(size_t)sr * 256 + k0 + seg * 8];
                *(ushort8*)&sA[row * 40 + seg * 8] = v;
            }
        } else {
#pragma unroll
            for (int l = 0; l < 4; ++l) {
                int p = t + l * 256;            // 0..1023
                int row = p >> 3, seg = p & 7;  // 4 floats per chunk
                int sr;
                if (AMODE == 1) { int g = s_idx[row]; sr = g < 0 ? 0 : g; }
                else            { sr = row0 + row; if (sr > M - 1) sr = M - 1; }
                const float4 v = *(const float4*)&Af[(size_t)sr * 256 + k0 + seg * 4];
                ushort4v h;
                h.x = f2b(v.x); h.y = f2b(v.y); h.z = f2b(v.z); h.w = f2b(v.w);
                *(ushort4v*)&sA[row * 40 + seg * 4] = h;
            }
        }
        // ---- stage B via global_load_lds (16B/lane) ----
#pragma unroll
        for (int l = 0; l < 2; ++l) {
            int p = t + l * 256;                // 0..511
            int n = p >> 2, seg = p & 3;
            const unsigned short* gsrc = Wt + (size_t)(colBase + n) * 256 + k0 + seg * 8;
            unsigned short* lbase = sB + (size_t)(p & ~63) * 8;   // wave-uniform 16B base
            __builtin_amdgcn_global_load_lds(
                (const __attribute__((address_space(1))) void*)gsrc,
                (__attribute__((address_space(3))) void*)lbase, 16, 0, 0);
        }
        __syncthreads();

        // ---- compute: 4x4 tiles of 16x16x32 per wave ----
        short8 af[4], bfr[4];
#pragma unroll
        for (int tr = 0; tr < 4; ++tr)
            af[tr] = *(const short8*)&sA[(wr * 64 + tr * 16 + l15) * 40 + quad * 8];
#pragma unroll
        for (int tc = 0; tc < 4; ++tc)
            bfr[tc] = *(const short8*)&sB[(wc * 64 + tc * 16 + l15) * 32 + quad * 8];
#pragma unroll
        for (int tr = 0; tr < 4; ++tr)
#pragma unroll
            for (int tc = 0; tc < 4; ++tc)
                acc[tr][tc] = __builtin_amdgcn_mfma_f32_16x16x32_bf16(
                    af[tr], bfr[tc], acc[tr][tc], 0, 0, 0);
    }

    // ---- epilogue/store ----
    float bcol[4];
#pragma unroll
    for (int tc = 0; tc < 4; ++tc)
        bcol[tc] = HAS_BIAS ? bias[colBase + wc * 64 + tc * 16 + l15] : 0.f;

#pragma unroll
    for (int tr = 0; tr < 4; ++tr) {
#pragma unroll
        for (int r = 0; r < 4; ++r) {
            int rowg = row0 + wr * 64 + tr * 16 + quad * 4 + r;
            if (rowg < M) {
                bool zero = HAS_MASK && (mask[rowg] < 0);
#pragma unroll
                for (int tc = 0; tc < 4; ++tc) {
                    int col = colBase + wc * 64 + tc * 16 + l15;
                    float v = zero ? 0.f : acc[tr][tc][r] + bcol[tc];
                    if (OUT_BF16)
                        ((unsigned short*)Cout)[(size_t)rowg * Nw + col] = f2b(v);
                    else
                        ((float*)Cout)[(size_t)rowg * Nw + col] = v;
                }
            }
        }
    }
}

// ---------------- fused epilogue: logits / softmax / agg / combine ----------------
__global__ __launch_bounds__(256) void epilogue_kernel(
    const float* __restrict__ table, const int* __restrict__ center_idx,
    const int* __restrict__ nb_idx_tab, const float* __restrict__ nb_wt_tab,
    const unsigned short* __restrict__ T, const unsigned short* __restrict__ cg,
    const float* __restrict__ W2, const float* __restrict__ b2,
    unsigned short* __restrict__ comb)
{
    const int b = blockIdx.x;
    const int t = threadIdx.x;

    __shared__ float s_cg[384];
    __shared__ float s_w2[128];
    __shared__ float s_logit[32];   // [h][k]
    __shared__ float s_wmx[32];     // softmax weights
    __shared__ int   s_nb[16];
    __shared__ float s_wt[16];

    const int ci   = center_idx[b];
    const int safe = ci < 0 ? 0 : ci;

    if (t < 16) {
        s_nb[t] = nb_idx_tab[(size_t)safe * KNB + t];
        s_wt[t] = nb_wt_tab[(size_t)safe * KNB + t];
    }
    if (t < 128) s_w2[t] = W2[t];
    for (int i = t; i < 384; i += 256) s_cg[i] = b2f(cg[(size_t)b * 384 + i]);
    const float ctr = (ci < 0) ? 0.f : table[(size_t)ci * 256 + t];
    __syncthreads();

    // logits: thread -> (k = t>>4, 8 channels at s*8)
    {
        const int k = t >> 4, s = t & 15;
        const int nb = s_nb[k];
        const int ns = nb < 0 ? 0 : nb;
        const ushort8 tv = *(const ushort8*)&T[(size_t)ns * 128 + s * 8];
        float partial = 0.f;
#pragma unroll
        for (int j = 0; j < 8; ++j) {
            int c = s * 8 + j;
            float v = b2f(tv[j]) + s_cg[c];
            float g = 0.5f * v * (1.f + erff(v * 0.70710678118654752440f));
            partial = fmaf(g, s_w2[c], partial);
        }
        partial += __shfl_xor(partial, 1, 64);
        partial += __shfl_xor(partial, 2, 64);
        partial += __shfl_xor(partial, 4, 64);
        if (s == 0) s_logit[k] = partial;          // head 0
        if (s == 8) s_logit[16 + k] = partial;     // head 1
    }
    __syncthreads();

    if (t < 2) {
        int h = t;
        bool hasany = false;
        for (int k = 0; k < 16; ++k) hasany |= (s_nb[k] >= 0);
        if (!hasany) {
            for (int k = 0; k < 16; ++k) s_wmx[h * 16 + k] = 1.f / 16.f;
        } else {
            float lg[16];
            float m = -INFINITY;
            for (int k = 0; k < 16; ++k) {
                float L = (s_nb[k] >= 0)
                    ? s_logit[h * 16 + k] + b2[h] + logf(s_wt[k] + 1e-8f)
                    : -INFINITY;
                lg[k] = L;
                if (L > m) m = L;
            }
            float ssum = 0.f, ex[16];
            for (int k = 0; k < 16; ++k) { ex[k] = expf(lg[k] - m); ssum += ex[k]; }
            float inv = 1.f / ssum;
            for (int k = 0; k < 16; ++k) s_wmx[h * 16 + k] = ex[k] * inv;
        }
    }
    __syncthreads();

    // agg + gated combine (t == output element e)
    const int h = t >> 7;
    float agg = 0.f;
#pragma unroll
    for (int k = 0; k < 16; ++k) {
        int nb = s_nb[k];
        int ns = nb < 0 ? 0 : nb;
        agg = fmaf(s_wmx[h * 16 + k], table[(size_t)ns * 256 + t], agg);
    }
    float gl   = s_cg[128 + t];
    float gate = 1.f / (1.f + expf(-gl));
    comb[(size_t)b * 256 + t] = f2b(ctr + gate * agg);
}

extern "C" void kernel_launch(void* const* d_in, const int* in_sizes, int n_in,
                              void* d_out, int out_size, void* d_ws, size_t ws_size,
                              hipStream_t stream)
{
    const int*   center_idx = (const int*)  d_in[0];
    const float* emb_table  = (const float*)d_in[1];
    const int*   nb_idx     = (const int*)  d_in[2];
    const float* nb_wt      = (const float*)d_in[3];
    const float* attn_W1    = (const float*)d_in[4];
    const float* attn_b1    = (const float*)d_in[5];
    const float* attn_W2    = (const float*)d_in[6];
    const float* attn_b2    = (const float*)d_in[7];
    const float* gate_W     = (const float*)d_in[8];
    const float* gate_b     = (const float*)d_in[9];
    const float* out_W      = (const float*)d_in[10];
    const float* out_b      = (const float*)d_in[11];
    float* out = (float*)d_out;

    char* ws = (char*)d_ws;
    unsigned short* T     = (unsigned short*)(ws + OFF_T);
    unsigned short* cgB   = (unsigned short*)(ws + OFF_CG);
    unsigned short* comb  = (unsigned short*)(ws + OFF_COMB);
    unsigned short* WcatT = (unsigned short*)(ws + OFF_WCAT);
    unsigned short* W1bT  = (unsigned short*)(ws + OFF_W1B);
    unsigned short* outWT = (unsigned short*)(ws + OFF_OUTW);
    float*          bcat  = (float*)         (ws + OFF_BCAT);

    // 1) repack weights to bf16 [n][k]
    repack_kernel<<<384, 256, 0, stream>>>(attn_W1, gate_W, out_W, attn_b1, gate_b,
                                           WcatT, W1bT, outWT, bcat);

    // 2) T = table @ W1_bot   [200000 x 256 x 128] -> bf16
    gemm_mfma<0, true, false, false><<<dim3((NTAB + 127) / 128, 1), 256, 0, stream>>>(
        emb_table, nullptr, nullptr, W1bT, 128, nullptr, nullptr, T, NTAB);

    // 3) cg = gather(center) @ [W1_top | gate_blockdiag] + bcat  [16384 x 256 x 384]
    gemm_mfma<1, true, true, false><<<dim3(BATCH / 128, 3), 256, 0, stream>>>(
        emb_table, nullptr, center_idx, WcatT, 384, bcat, nullptr, cgB, BATCH);

    // 4) fused epilogue -> comb (bf16)
    epilogue_kernel<<<BATCH, 256, 0, stream>>>(
        emb_table, center_idx, nb_idx, nb_wt, T, cgB, attn_W2, attn_b2, comb);

    // 5) out = comb @ out_W^T + out_b, invalid rows -> 0
    gemm_mfma<2, false, true, true><<<dim3(BATCH / 128, 2), 256, 0, stream>>>(
        nullptr, comb, nullptr, outWT, 256, out_b, center_idx, out, BATCH);
}